// Round 14
// baseline (608.975 us; speedup 1.0000x reference)
//
#include <hip/hip_runtime.h>
#include <hip/hip_bf16.h>

typedef unsigned short u16;
typedef unsigned int   u32;
typedef _Float16 half2_t __attribute__((ext_vector_type(2)));
typedef short    bf16x8 __attribute__((ext_vector_type(8)));
typedef float    f32x4  __attribute__((ext_vector_type(4)));
typedef u32      u32x4v __attribute__((ext_vector_type(4)));

// Problem dims: B=128, T=512, V=50000, NT=24, E=128, H=256, Hd=128
#define TT   512

__device__ __forceinline__ float sigf(float x)  { return 1.0f / (1.0f + __expf(-x)); }
__device__ __forceinline__ float tanhf_(float x){ return 1.0f - 2.0f / (__expf(2.0f * x) + 1.0f); }

__device__ __forceinline__ u16 f2bf(float x) {
  __hip_bfloat16 h = __float2bfloat16(x);
  return *reinterpret_cast<u16*>(&h);
}
__device__ __forceinline__ float bf2f(u16 u) { return __uint_as_float(((u32)u) << 16); }
__device__ __forceinline__ u32 pk2(float a, float b) {
  return (u32)f2bf(a) | ((u32)f2bf(b) << 16);
}
__device__ __forceinline__ u16 f2h(float x) {
  _Float16 h = (_Float16)x;
  union { _Float16 f; u16 u; } c; c.f = h; return c.u;
}
__device__ __forceinline__ half2_t u2h2(u32 v) {
  union { u32 u; half2_t h; } c; c.u = v; return c.h;
}

// ---------------------------------------------------------------------------
// K0: weight prep.
// Wb bf16 [1024][128] PERMUTED rows: row n = dir*512 + u*4 + g <- W_dir[g*128+u]
// bias f32 [1024] same permutation. Whhb bf16 [2][512][128]. Wout16 [24][128].
// ---------------------------------------------------------------------------
__global__ __launch_bounds__(256) void prep_k(
    const float* __restrict__ Wih_f, const float* __restrict__ Wih_b,
    const float* __restrict__ Whh_f, const float* __restrict__ Whh_b,
    const float* __restrict__ bih_f, const float* __restrict__ bhh_f,
    const float* __restrict__ bih_b, const float* __restrict__ bhh_b,
    const float* __restrict__ W_out,
    u16* __restrict__ Wb, u16* __restrict__ Whhb, float* __restrict__ bias,
    u32* __restrict__ Wout16)
{
  int i = blockIdx.x * 256 + threadIdx.x;   // 131072 threads
  {
    int n = i >> 7, k = i & 127;
    int d = n >> 9, rem = n & 511, uu = rem >> 2, g = rem & 3;
    const float* W = d ? Wih_b : Wih_f;
    Wb[i] = f2bf(W[(g * 128 + uu) * 128 + k]);
  }
  {
    int d = i >> 16, rem = i & 65535, n = rem >> 7, k = rem & 127;
    const float* W = d ? Whh_b : Whh_f;
    Whhb[i] = f2bf(W[n * 128 + k]);
  }
  if (i < 1024) {
    int d = i >> 9, rem = i & 511, uu = rem >> 2, g = rem & 3;
    int src = g * 128 + uu;
    bias[i] = d ? (bih_b[src] + bhh_b[src]) : (bih_f[src] + bhh_f[src]);
  }
  if (i < 3072) {
    Wout16[i] = (u32)f2h(W_out[2 * i]) | ((u32)f2h(W_out[2 * i + 1]) << 16);
  }
}

// ---------------------------------------------------------------------------
// K1: embedding gather -> bf16 xe [65536][128]
// ---------------------------------------------------------------------------
__global__ __launch_bounds__(256) void embed_k(
    const int* __restrict__ x, const float* __restrict__ emb, u16* __restrict__ xe)
{
  const int tid = threadIdx.x;
  const int r = blockIdx.x * 8 + (tid >> 5);
  const int lane = tid & 31;
  int token = x[r];
  float4 v = *(const float4*)&emb[(size_t)token * 128 + lane * 4];
  uint2 p; p.x = pk2(v.x, v.y); p.y = pk2(v.z, v.w);
  *(uint2*)&xe[(size_t)r * 128 + lane * 4] = p;
}

// ---------------------------------------------------------------------------
// K2: gates GEMM via bf16 MFMA 16x16x32 (permuted column space).
// ---------------------------------------------------------------------------
__global__ __launch_bounds__(256, 2) void gates_mfma_k(
    const u16* __restrict__ xe, const u16* __restrict__ Wb,
    const float* __restrict__ bias, u16* __restrict__ Gout)
{
  const int tid = threadIdx.x;
  const int wid = tid >> 6, l = tid & 63;
  const int wm = wid >> 1, wn = wid & 1;
  const int M0 = blockIdx.y * 128, N0 = blockIdx.x * 128;
  const int lr = l & 15, lk = l >> 4;

  f32x4 acc[4][4];
#pragma unroll
  for (int i = 0; i < 4; ++i)
#pragma unroll
    for (int j = 0; j < 4; ++j) acc[i][j] = (f32x4){0.f, 0.f, 0.f, 0.f};

#pragma unroll
  for (int ks = 0; ks < 4; ++ks) {
    bf16x8 a[4], b[4];
#pragma unroll
    for (int mi = 0; mi < 4; ++mi)
      a[mi] = *(const bf16x8*)&xe[(size_t)(M0 + wm * 64 + mi * 16 + lr) * 128 + ks * 32 + lk * 8];
#pragma unroll
    for (int ni = 0; ni < 4; ++ni)
      b[ni] = *(const bf16x8*)&Wb[(size_t)(N0 + wn * 64 + ni * 16 + lr) * 128 + ks * 32 + lk * 8];
#pragma unroll
    for (int mi = 0; mi < 4; ++mi)
#pragma unroll
      for (int ni = 0; ni < 4; ++ni)
        acc[mi][ni] = __builtin_amdgcn_mfma_f32_16x16x32_bf16(a[mi], b[ni], acc[mi][ni], 0, 0, 0);
  }

  float bcol[4];
#pragma unroll
  for (int ni = 0; ni < 4; ++ni) bcol[ni] = bias[N0 + wn * 64 + ni * 16 + lr];

  __shared__ u16 cs[128][136];
#pragma unroll
  for (int mi = 0; mi < 4; ++mi)
#pragma unroll
    for (int ni = 0; ni < 4; ++ni) {
      int col = wn * 64 + ni * 16 + lr;
#pragma unroll
      for (int r = 0; r < 4; ++r) {
        int row = wm * 64 + mi * 16 + lk * 4 + r;
        cs[row][col] = f2bf(acc[mi][ni][r] + bcol[ni]);
      }
    }
  __syncthreads();
  {
    int row = tid >> 1, c0 = (tid & 1) * 64;
    u16* dst = &Gout[(size_t)(M0 + row) * 1024 + N0 + c0];
#pragma unroll
    for (int q = 0; q < 8; ++q)
      *(uint4*)&dst[q * 8] = *(const uint4*)&cs[row][c0 + q * 8];
  }
}

// ---------------------------------------------------------------------------
// K3: LSTM recurrence via MFMA, v8.
// v7 (broadcast-A, chunked 8-deep G prefetch) + two changes:
//  (a) H stores BATCHED per chunk via ping-pong register stash (hsA/hsB):
//      the per-step global-store write-ack is no longer drained at every
//      step's barrier — one drain region per 8 steps (with G loads).
//  (b) 16 INDEPENDENT MFMA partials (no 4-deep acc chain); epilogue sums
//      the [0] elements (3 adds/gate) -> shorter serial path.
// One block per (dir,sample) = 256 blocks x 512 threads (8 waves).
// ---------------------------------------------------------------------------
__global__ __launch_bounds__(512, 1) void lstm_mfma_k(
    const u16* __restrict__ G, const u16* __restrict__ Whhb,
    u16* __restrict__ Hout)
{
  const int bid = blockIdx.x;         // 0..255
  const int dir = bid >> 7;
  const int b   = bid & 127;
  const int tid = threadIdx.x;
  const int w = tid >> 6, l = tid & 63;
  const int lr = l & 15, lk = l >> 4;
  const int u = 16 * w + lr;          // owned unit column

  // B-fragments: gate g, k-slice ks: Whh[g*128+u][ks*32+lk*8 ..+8]
  const u16* wbase = Whhb + ((size_t)dir << 16);
  bf16x8 B[4][4];
#pragma unroll
  for (int g = 0; g < 4; ++g)
#pragma unroll
    for (int ks = 0; ks < 4; ++ks)
      B[g][ks] = *(const bf16x8*)&wbase[(size_t)(g * 128 + u) * 128 + ks * 32 + lk * 8];

  __shared__ __align__(16) u16 hl[2][160];   // h bf16, double buffer

  for (int i = tid; i < 2 * 160; i += 512) ((u16*)hl)[i] = 0;

  float cc = 0.f;
  const int ts = dir ? -1 : 1;
  const int t0 = dir ? (TT - 1) : 0;
  const long gstride = (long)ts * 1024;
  const long hstride = (long)ts * 256;

  const u16* gptr = G + ((size_t)b * 512 + t0) * 1024 + dir * 512 + u * 4;
  u16*       hptr = Hout + ((size_t)b * 512 + t0) * 256 + dir * 128 + u;

  // preload chunk 0 (steps 0..7) into bank qa
  ushort4 qa[8], qb[8];
#pragma unroll
  for (int j = 0; j < 8; ++j)
    qa[j] = *(const ushort4*)(gptr + j * gstride);
  const u16* gpf = gptr + 8 * gstride;   // next-chunk load base

  u16 hsA[8], hsB[8];
  __syncthreads();

  // one LSTM step: Q = preacts, P = step parity, HS[J] = h stash slot
#define LSTM_STEP(Q, P, HS, J) { \
    bf16x8 A0 = *(const bf16x8*)&hl[P][lk * 8]; \
    bf16x8 A1 = *(const bf16x8*)&hl[P][32 + lk * 8]; \
    bf16x8 A2 = *(const bf16x8*)&hl[P][64 + lk * 8]; \
    bf16x8 A3 = *(const bf16x8*)&hl[P][96 + lk * 8]; \
    f32x4 zz = (f32x4){0.f, 0.f, 0.f, 0.f}; \
    f32x4 p00 = zz, p01 = zz, p02 = zz, p03 = zz; \
    f32x4 p10 = zz, p11 = zz, p12 = zz, p13 = zz; \
    f32x4 p20 = zz, p21 = zz, p22 = zz, p23 = zz; \
    f32x4 p30 = zz, p31 = zz, p32 = zz, p33 = zz; \
    p00 = __builtin_amdgcn_mfma_f32_16x16x32_bf16(A0, B[0][0], p00, 0, 0, 0); \
    p01 = __builtin_amdgcn_mfma_f32_16x16x32_bf16(A1, B[0][1], p01, 0, 0, 0); \
    p02 = __builtin_amdgcn_mfma_f32_16x16x32_bf16(A2, B[0][2], p02, 0, 0, 0); \
    p03 = __builtin_amdgcn_mfma_f32_16x16x32_bf16(A3, B[0][3], p03, 0, 0, 0); \
    p10 = __builtin_amdgcn_mfma_f32_16x16x32_bf16(A0, B[1][0], p10, 0, 0, 0); \
    p11 = __builtin_amdgcn_mfma_f32_16x16x32_bf16(A1, B[1][1], p11, 0, 0, 0); \
    p12 = __builtin_amdgcn_mfma_f32_16x16x32_bf16(A2, B[1][2], p12, 0, 0, 0); \
    p13 = __builtin_amdgcn_mfma_f32_16x16x32_bf16(A3, B[1][3], p13, 0, 0, 0); \
    p20 = __builtin_amdgcn_mfma_f32_16x16x32_bf16(A0, B[2][0], p20, 0, 0, 0); \
    p21 = __builtin_amdgcn_mfma_f32_16x16x32_bf16(A1, B[2][1], p21, 0, 0, 0); \
    p22 = __builtin_amdgcn_mfma_f32_16x16x32_bf16(A2, B[2][2], p22, 0, 0, 0); \
    p23 = __builtin_amdgcn_mfma_f32_16x16x32_bf16(A3, B[2][3], p23, 0, 0, 0); \
    p30 = __builtin_amdgcn_mfma_f32_16x16x32_bf16(A0, B[3][0], p30, 0, 0, 0); \
    p31 = __builtin_amdgcn_mfma_f32_16x16x32_bf16(A1, B[3][1], p31, 0, 0, 0); \
    p32 = __builtin_amdgcn_mfma_f32_16x16x32_bf16(A2, B[3][2], p32, 0, 0, 0); \
    p33 = __builtin_amdgcn_mfma_f32_16x16x32_bf16(A3, B[3][3], p33, 0, 0, 0); \
    float gi = ((p00[0] + p01[0]) + (p02[0] + p03[0])) + bf2f((Q).x); \
    float gf = ((p10[0] + p11[0]) + (p12[0] + p13[0])) + bf2f((Q).y); \
    float gg = ((p20[0] + p21[0]) + (p22[0] + p23[0])) + bf2f((Q).z); \
    float go = ((p30[0] + p31[0]) + (p32[0] + p33[0])) + bf2f((Q).w); \
    float iv = sigf(gi), fv = sigf(gf), gv = tanhf_(gg), ov = sigf(go); \
    cc = fv * cc + iv * gv; \
    float hv = ov * tanhf_(cc); \
    if (lk == 0) hl[(P) ^ 1][u] = f2bf(hv); \
    HS[J] = f2h(hv); \
    __syncthreads(); }

  // one 8-step chunk: store prev chunk's h bank, load next G bank, run 8 steps
#define LSTM_CHUNK(QC, QN, HSW, HSS, DOLOAD, DOSTORE) { \
    if (DOSTORE) { \
      if (lk == 0) { \
        _Pragma("unroll") \
        for (int j = 0; j < 8; ++j) hptr[j * hstride] = HSS[j]; \
      } \
      hptr += 8 * hstride; \
    } \
    if (DOLOAD) { \
      _Pragma("unroll") \
      for (int j = 0; j < 8; ++j) QN[j] = *(const ushort4*)(gpf + j * gstride); \
      gpf += 8 * gstride; \
    } \
    LSTM_STEP(QC[0], 0, HSW, 0) \
    LSTM_STEP(QC[1], 1, HSW, 1) \
    LSTM_STEP(QC[2], 0, HSW, 2) \
    LSTM_STEP(QC[3], 1, HSW, 3) \
    LSTM_STEP(QC[4], 0, HSW, 4) \
    LSTM_STEP(QC[5], 1, HSW, 5) \
    LSTM_STEP(QC[6], 0, HSW, 6) \
    LSTM_STEP(QC[7], 1, HSW, 7) }

  // chunk 0: loads chunk 1 into qb, writes hsA, no store yet
  LSTM_CHUNK(qa, qb, hsA, hsB, true, false)
  // chunks 1..62 in ping-pong pairs
  for (int p = 0; p < 31; ++p) {
    LSTM_CHUNK(qb, qa, hsB, hsA, true, true)
    LSTM_CHUNK(qa, qb, hsA, hsB, true, true)
  }
  // chunk 63: consumes qb, writes hsB, stores hsA, no loads
  LSTM_CHUNK(qb, qa, hsB, hsA, false, true)

#undef LSTM_CHUNK
#undef LSTM_STEP

  // tail: store last chunk's h bank
  if (lk == 0) {
#pragma unroll
    for (int j = 0; j < 8; ++j) hptr[j * hstride] = hsB[j];
  }
}

// ---------------------------------------------------------------------------
// K4: emissions = h @ W_out^T + b_out.  H f16, W_out f16-packed in LDS, fdot2.
// ---------------------------------------------------------------------------
__global__ __launch_bounds__(256) void emis_k(
    const u16* __restrict__ Hb, const u32* __restrict__ Wout16,
    const float* __restrict__ b_out, float* __restrict__ em)
{
  __shared__ __align__(16) u32 wl2[24 * 128];   // 12 KB
  __shared__ float bo[24];
  const int tid = threadIdx.x;
  for (int i = tid; i < 3072; i += 256) wl2[i] = Wout16[i];
  if (tid < 24) bo[tid] = b_out[tid];
  __syncthreads();

  const int m = blockIdx.x * 256 + tid;
  float acc[24];
#pragma unroll
  for (int tg = 0; tg < 24; ++tg) acc[tg] = bo[tg];

  const u32* h2 = (const u32*)(Hb + (size_t)m * 256);
  for (int ck = 0; ck < 16; ++ck) {          // 8 f16 per chunk
    uint4 hv = *(const uint4*)(h2 + ck * 4);
#pragma unroll
    for (int tg = 0; tg < 24; ++tg) {
      u32x4v wv = *(const u32x4v*)&wl2[tg * 128 + ck * 4];
      float a = acc[tg];
      a = __builtin_amdgcn_fdot2(u2h2(hv.x), u2h2(wv.x), a, false);
      a = __builtin_amdgcn_fdot2(u2h2(hv.y), u2h2(wv.y), a, false);
      a = __builtin_amdgcn_fdot2(u2h2(hv.z), u2h2(wv.z), a, false);
      a = __builtin_amdgcn_fdot2(u2h2(hv.w), u2h2(wv.w), a, false);
      acc[tg] = a;
    }
  }
#pragma unroll
  for (int t6 = 0; t6 < 6; ++t6) {
    float4 o;
    o.x = acc[t6*4+0]; o.y = acc[t6*4+1]; o.z = acc[t6*4+2]; o.w = acc[t6*4+3];
    *(float4*)&em[(size_t)m * 24 + t6 * 4] = o;
  }
}

// ---------------------------------------------------------------------------
// K5: CRF forward scan, probability domain, all cross-lane via __shfl.
// ---------------------------------------------------------------------------
__device__ __forceinline__ int get_mask(const void* mp, int idx, bool byte_mode) {
  return byte_mode ? (int)((const unsigned char*)mp)[idx] : ((const int*)mp)[idx];
}

__global__ __launch_bounds__(64) void crf_k(
    const float* __restrict__ em, const int* __restrict__ tags,
    const void* __restrict__ maskp, const float* __restrict__ trans,
    const float* __restrict__ start_tr, const float* __restrict__ end_tr,
    float* __restrict__ out)
{
  const int b = blockIdx.x;
  const int tid = threadIdx.x;
  const bool byte_mode = (*(const u32*)maskp != 1u);
  const bool act = (tid < 48);
  const int j  = (tid < 24) ? tid : (act ? tid - 24 : 0);
  const int i0 = (tid < 24) ? 0 : 12;
  const int partner = (tid < 24) ? tid + 24 : tid - 24;

  int cnt = 0;
  for (int t = tid; t < TT; t += 64) cnt += get_mask(maskp, b * TT + t, byte_mode);
#pragma unroll
  for (int off = 32; off > 0; off >>= 1) cnt += __shfl_down(cnt, off);
  cnt = __shfl(cnt, 0);

  float Texp[12];
  if (act) {
#pragma unroll
    for (int k = 0; k < 12; ++k) Texp[k] = __expf(trans[(i0 + k) * 24 + j]);
  } else {
#pragma unroll
    for (int k = 0; k < 12; ++k) Texp[k] = 0.f;
  }

  float sc0 = act ? (start_tr[j] + em[(size_t)(b * TT) * 24 + j]) : -1e30f;
  float m = sc0;
#pragma unroll
  for (int off = 32; off > 0; off >>= 1) m = fmaxf(m, __shfl_xor(m, off));
  float P = act ? __expf(sc0 - m) : 0.f;
  float logC = m;

  float em_next = 0.f;
  if (act && cnt > 1) em_next = em[(size_t)(b * TT + 1) * 24 + j];

  for (int t = 1; t < cnt; ++t) {
    float em_cur = em_next;
    if (act && t + 1 < cnt) em_next = em[(size_t)(b * TT + t + 1) * 24 + j];

    float s0 = 0.f, s1 = 0.f, s2 = 0.f;
#pragma unroll
    for (int k = 0; k < 4; ++k)  s0 += __shfl(P, i0 + k)     * Texp[k];
#pragma unroll
    for (int k = 4; k < 8; ++k)  s1 += __shfl(P, i0 + k)     * Texp[k];
#pragma unroll
    for (int k = 8; k < 12; ++k) s2 += __shfl(P, i0 + k)     * Texp[k];
    float sh = (s0 + s1) + s2;
    float so = __shfl(sh, partner);
    float tot = sh + so;
    P = act ? (__expf(em_cur) * tot) : 0.f;

    if ((t & 3) == 0) {          // renormalize every 4 steps
      float mm = P;
#pragma unroll
      for (int off = 32; off > 0; off >>= 1) mm = fmaxf(mm, __shfl_xor(mm, off));
      P = P / mm;
      logC += __logf(mm);
    }
  }

  float z = (tid < 24) ? P * __expf(end_tr[tid]) : 0.f;
#pragma unroll
  for (int off = 32; off > 0; off >>= 1) z += __shfl_xor(z, off);
  float lzv = logC + __logf(z);

  float part = 0.f;
  for (int t = tid; t < TT; t += 64) {
    if (t >= 1 && t < cnt) {
      int tp = tags[b * TT + t - 1], tc = tags[b * TT + t];
      part += trans[tp * 24 + tc] + em[((size_t)(b * TT + t)) * 24 + tc];
    }
  }
#pragma unroll
  for (int off = 32; off > 0; off >>= 1) part += __shfl_down(part, off);
  if (tid == 0) {
    int t0g = tags[b * TT];
    float gold = start_tr[t0g] + em[(size_t)(b * TT) * 24 + t0g] + part;
    gold += end_tr[tags[b * TT + cnt - 1]];
    atomicAdd(out, (lzv - gold) * (1.0f / 128.0f));
  }
}

// ---------------------------------------------------------------------------
extern "C" void kernel_launch(void* const* d_in, const int* in_sizes, int n_in,
                              void* d_out, int out_size, void* d_ws, size_t ws_size,
                              hipStream_t stream) {
  const int*   x     = (const int*)d_in[0];
  const int*   tags  = (const int*)d_in[1];
  const void*  mask  = d_in[2];
  const float* emb   = (const float*)d_in[3];
  const float* Wih_f = (const float*)d_in[4];
  const float* Whh_f = (const float*)d_in[5];
  const float* bih_f = (const float*)d_in[6];
  const float* bhh_f = (const float*)d_in[7];
  const float* Wih_b = (const float*)d_in[8];
  const float* Whh_b = (const float*)d_in[9];
  const float* bih_b = (const float*)d_in[10];
  const float* bhh_b = (const float*)d_in[11];
  const float* W_out = (const float*)d_in[12];
  const float* b_out = (const float*)d_in[13];
  const float* trans = (const float*)d_in[14];
  const float* st_tr = (const float*)d_in[15];
  const float* en_tr = (const float*)d_in[16];

  u16*   Gb     = (u16*)d_ws;                              // [65536][1024] bf16
  u16*   Hb     = Gb + (size_t)65536 * 1024;               // [65536][256]  f16
  float* em     = (float*)(Hb + (size_t)65536 * 256);      // [65536][24]   f32
  float* bias   = em + (size_t)65536 * 24;                 // [1024]
  u16*   Wb     = (u16*)(bias + 1024);                     // [1024][128]   bf16
  u16*   Whhb   = Wb + 131072;                             // [2][512][128] bf16
  u32*   Wout16 = (u32*)(Whhb + 131072);                   // [24][128]     f16x2
  u16*   xe     = Hb;  // alias: xe dead before lstm writes Hb

  prep_k<<<512, 256, 0, stream>>>(Wih_f, Wih_b, Whh_f, Whh_b,
                                  bih_f, bhh_f, bih_b, bhh_b, W_out,
                                  Wb, Whhb, bias, Wout16);
  embed_k<<<8192, 256, 0, stream>>>(x, emb, xe);
  gates_mfma_k<<<dim3(8, 512), 256, 0, stream>>>(xe, Wb, bias, Gb);
  lstm_mfma_k<<<256, 512, 0, stream>>>(Gb, Whhb, Hb);
  emis_k<<<256, 256, 0, stream>>>(Hb, Wout16, b_out, em);
  (void)hipMemsetAsync(d_out, 0, sizeof(float), stream);
  crf_k<<<128, 64, 0, stream>>>(em, tags, mask, trans, st_tr, en_tr, (float*)d_out);
}

// Round 15
// 606.054 us; speedup vs baseline: 1.0048x; 1.0048x over previous
//
#include <hip/hip_runtime.h>
#include <hip/hip_bf16.h>

typedef unsigned short u16;
typedef unsigned int   u32;
typedef _Float16 half2_t __attribute__((ext_vector_type(2)));
typedef short    bf16x8 __attribute__((ext_vector_type(8)));
typedef float    f32x4  __attribute__((ext_vector_type(4)));
typedef u32      u32x4v __attribute__((ext_vector_type(4)));

// Problem dims: B=128, T=512, V=50000, NT=24, E=128, H=256, Hd=128
#define TT   512

__device__ __forceinline__ float sigf(float x)  { return 1.0f / (1.0f + __expf(-x)); }
__device__ __forceinline__ float tanhf_(float x){ return 1.0f - 2.0f / (__expf(2.0f * x) + 1.0f); }

__device__ __forceinline__ u16 f2bf(float x) {
  __hip_bfloat16 h = __float2bfloat16(x);
  return *reinterpret_cast<u16*>(&h);
}
__device__ __forceinline__ float bf2f(u16 u) { return __uint_as_float(((u32)u) << 16); }
__device__ __forceinline__ u32 pk2(float a, float b) {
  return (u32)f2bf(a) | ((u32)f2bf(b) << 16);
}
__device__ __forceinline__ u16 f2h(float x) {
  _Float16 h = (_Float16)x;
  union { _Float16 f; u16 u; } c; c.f = h; return c.u;
}
__device__ __forceinline__ half2_t u2h2(u32 v) {
  union { u32 u; half2_t h; } c; c.u = v; return c.h;
}

// ---------------------------------------------------------------------------
// K0: weight prep.
// Wb bf16 [1024][128] PERMUTED rows: row n = dir*512 + u*4 + g <- W_dir[g*128+u]
// bias f32 [1024] same permutation. Whhb bf16 [2][512][128]. Wout16 [24][128].
// ---------------------------------------------------------------------------
__global__ __launch_bounds__(256) void prep_k(
    const float* __restrict__ Wih_f, const float* __restrict__ Wih_b,
    const float* __restrict__ Whh_f, const float* __restrict__ Whh_b,
    const float* __restrict__ bih_f, const float* __restrict__ bhh_f,
    const float* __restrict__ bih_b, const float* __restrict__ bhh_b,
    const float* __restrict__ W_out,
    u16* __restrict__ Wb, u16* __restrict__ Whhb, float* __restrict__ bias,
    u32* __restrict__ Wout16)
{
  int i = blockIdx.x * 256 + threadIdx.x;   // 131072 threads
  {
    int n = i >> 7, k = i & 127;
    int d = n >> 9, rem = n & 511, uu = rem >> 2, g = rem & 3;
    const float* W = d ? Wih_b : Wih_f;
    Wb[i] = f2bf(W[(g * 128 + uu) * 128 + k]);
  }
  {
    int d = i >> 16, rem = i & 65535, n = rem >> 7, k = rem & 127;
    const float* W = d ? Whh_b : Whh_f;
    Whhb[i] = f2bf(W[n * 128 + k]);
  }
  if (i < 1024) {
    int d = i >> 9, rem = i & 511, uu = rem >> 2, g = rem & 3;
    int src = g * 128 + uu;
    bias[i] = d ? (bih_b[src] + bhh_b[src]) : (bih_f[src] + bhh_f[src]);
  }
  if (i < 3072) {
    Wout16[i] = (u32)f2h(W_out[2 * i]) | ((u32)f2h(W_out[2 * i + 1]) << 16);
  }
}

// ---------------------------------------------------------------------------
// K1: embedding gather -> bf16 xe [65536][128]
// ---------------------------------------------------------------------------
__global__ __launch_bounds__(256) void embed_k(
    const int* __restrict__ x, const float* __restrict__ emb, u16* __restrict__ xe)
{
  const int tid = threadIdx.x;
  const int r = blockIdx.x * 8 + (tid >> 5);
  const int lane = tid & 31;
  int token = x[r];
  float4 v = *(const float4*)&emb[(size_t)token * 128 + lane * 4];
  uint2 p; p.x = pk2(v.x, v.y); p.y = pk2(v.z, v.w);
  *(uint2*)&xe[(size_t)r * 128 + lane * 4] = p;
}

// ---------------------------------------------------------------------------
// K2: gates GEMM via bf16 MFMA 16x16x32 (permuted column space).
// ---------------------------------------------------------------------------
__global__ __launch_bounds__(256, 2) void gates_mfma_k(
    const u16* __restrict__ xe, const u16* __restrict__ Wb,
    const float* __restrict__ bias, u16* __restrict__ Gout)
{
  const int tid = threadIdx.x;
  const int wid = tid >> 6, l = tid & 63;
  const int wm = wid >> 1, wn = wid & 1;
  const int M0 = blockIdx.y * 128, N0 = blockIdx.x * 128;
  const int lr = l & 15, lk = l >> 4;

  f32x4 acc[4][4];
#pragma unroll
  for (int i = 0; i < 4; ++i)
#pragma unroll
    for (int j = 0; j < 4; ++j) acc[i][j] = (f32x4){0.f, 0.f, 0.f, 0.f};

#pragma unroll
  for (int ks = 0; ks < 4; ++ks) {
    bf16x8 a[4], b[4];
#pragma unroll
    for (int mi = 0; mi < 4; ++mi)
      a[mi] = *(const bf16x8*)&xe[(size_t)(M0 + wm * 64 + mi * 16 + lr) * 128 + ks * 32 + lk * 8];
#pragma unroll
    for (int ni = 0; ni < 4; ++ni)
      b[ni] = *(const bf16x8*)&Wb[(size_t)(N0 + wn * 64 + ni * 16 + lr) * 128 + ks * 32 + lk * 8];
#pragma unroll
    for (int mi = 0; mi < 4; ++mi)
#pragma unroll
      for (int ni = 0; ni < 4; ++ni)
        acc[mi][ni] = __builtin_amdgcn_mfma_f32_16x16x32_bf16(a[mi], b[ni], acc[mi][ni], 0, 0, 0);
  }

  float bcol[4];
#pragma unroll
  for (int ni = 0; ni < 4; ++ni) bcol[ni] = bias[N0 + wn * 64 + ni * 16 + lr];

  __shared__ u16 cs[128][136];
#pragma unroll
  for (int mi = 0; mi < 4; ++mi)
#pragma unroll
    for (int ni = 0; ni < 4; ++ni) {
      int col = wn * 64 + ni * 16 + lr;
#pragma unroll
      for (int r = 0; r < 4; ++r) {
        int row = wm * 64 + mi * 16 + lk * 4 + r;
        cs[row][col] = f2bf(acc[mi][ni][r] + bcol[ni]);
      }
    }
  __syncthreads();
  {
    int row = tid >> 1, c0 = (tid & 1) * 64;
    u16* dst = &Gout[(size_t)(M0 + row) * 1024 + N0 + c0];
#pragma unroll
    for (int q = 0; q < 8; ++q)
      *(uint4*)&dst[q * 8] = *(const uint4*)&cs[row][c0 + q * 8];
  }
}

// ---------------------------------------------------------------------------
// K3: LSTM recurrence via MFMA, v9 = v5 body + chunked G prefetch.
// One block per (dir,sample) = 256 blocks x 512 threads (8 waves).
// v5 (best measured): per-lane A reads from hl[2][16][136] (rows 1..15 zero),
// guarded lk==0 in-register epilogue, chained 4-MFMA acc, per-step delayed
// H store. v7's addition: G preacts loaded 8-steps-at-a-time into ping-pong
// register banks (qa/qb, static indices) so the HBM load latency + barrier
// drain is paid once per 8 steps instead of every step.
// ---------------------------------------------------------------------------
__global__ __launch_bounds__(512, 1) void lstm_mfma_k(
    const u16* __restrict__ G, const u16* __restrict__ Whhb,
    u16* __restrict__ Hout)
{
  const int bid = blockIdx.x;         // 0..255
  const int dir = bid >> 7;
  const int b   = bid & 127;
  const int tid = threadIdx.x;
  const int w = tid >> 6, l = tid & 63;
  const int lr = l & 15, lk = l >> 4;
  const int u = 16 * w + lr;          // owned unit column

  // B-fragments: gate g, k-slice ks: Whh[g*128+u][ks*32+lk*8 ..+8]
  const u16* wbase = Whhb + ((size_t)dir << 16);
  bf16x8 B[4][4];
#pragma unroll
  for (int g = 0; g < 4; ++g)
#pragma unroll
    for (int ks = 0; ks < 4; ++ks)
      B[g][ks] = *(const bf16x8*)&wbase[(size_t)(g * 128 + u) * 128 + ks * 32 + lk * 8];

  __shared__ u16 hl[2][16][136];      // h bf16, dbuf; rows 1..15 stay zero

  for (int i = tid; i < 2 * 16 * 136; i += 512) ((u16*)hl)[i] = 0;

  float cc = 0.f;                      // cell state (lanes lk==0 only)
  const int ts = dir ? -1 : 1;
  const int t0 = dir ? (TT - 1) : 0;
  const long gstride = (long)ts * 1024;
  const long hstride = (long)ts * 256;

  const u16* gptr = G + ((size_t)b * 512 + t0) * 1024 + dir * 512 + u * 4;
  u16*       hptr = Hout + ((size_t)b * 512 + t0) * 256 + dir * 128 + u;

  // preload chunk 0 (steps 0..7) into bank qa
  ushort4 qa[8], qb[8];
#pragma unroll
  for (int j = 0; j < 8; ++j)
    qa[j] = *(const ushort4*)(gptr + j * gstride);
  const u16* gpf = gptr + 8 * gstride;   // next-chunk load base

  u16 hprev = 0;
  __syncthreads();

  // one LSTM step (v5 body): Q = preacts, P = step parity
#define LSTM_STEP(Q, P, DOSTORE) { \
    if (DOSTORE) { if (lk == 0) *hptr = hprev; hptr += hstride; } \
    bf16x8 A[4]; \
    _Pragma("unroll") \
    for (int ks = 0; ks < 4; ++ks) \
      A[ks] = *(const bf16x8*)&hl[P][lr][ks * 32 + lk * 8]; \
    f32x4 ac0 = (f32x4){0.f,0.f,0.f,0.f}, ac1 = (f32x4){0.f,0.f,0.f,0.f}; \
    f32x4 ac2 = (f32x4){0.f,0.f,0.f,0.f}, ac3 = (f32x4){0.f,0.f,0.f,0.f}; \
    _Pragma("unroll") \
    for (int ks = 0; ks < 4; ++ks) { \
      ac0 = __builtin_amdgcn_mfma_f32_16x16x32_bf16(A[ks], B[0][ks], ac0, 0, 0, 0); \
      ac1 = __builtin_amdgcn_mfma_f32_16x16x32_bf16(A[ks], B[1][ks], ac1, 0, 0, 0); \
      ac2 = __builtin_amdgcn_mfma_f32_16x16x32_bf16(A[ks], B[2][ks], ac2, 0, 0, 0); \
      ac3 = __builtin_amdgcn_mfma_f32_16x16x32_bf16(A[ks], B[3][ks], ac3, 0, 0, 0); \
    } \
    if (lk == 0) { \
      float gi = ac0[0] + bf2f((Q).x); \
      float gf = ac1[0] + bf2f((Q).y); \
      float gg = ac2[0] + bf2f((Q).z); \
      float go = ac3[0] + bf2f((Q).w); \
      float iv = sigf(gi), fv = sigf(gf), gv = tanhf_(gg), ov = sigf(go); \
      cc = fv * cc + iv * gv; \
      float hv = ov * tanhf_(cc); \
      hl[(P) ^ 1][0][u] = f2bf(hv); \
      hprev = f2h(hv); \
    } \
    __syncthreads(); }

  // one 8-step chunk consuming bank QC; optionally loads next chunk into QN
#define LSTM_CHUNK(QC, QN, DOLOAD, FIRST) { \
    if (DOLOAD) { \
      _Pragma("unroll") \
      for (int j = 0; j < 8; ++j) \
        QN[j] = *(const ushort4*)(gpf + j * gstride); \
      gpf += 8 * gstride; \
    } \
    LSTM_STEP(QC[0], 0, !(FIRST)) \
    LSTM_STEP(QC[1], 1, true) \
    LSTM_STEP(QC[2], 0, true) \
    LSTM_STEP(QC[3], 1, true) \
    LSTM_STEP(QC[4], 0, true) \
    LSTM_STEP(QC[5], 1, true) \
    LSTM_STEP(QC[6], 0, true) \
    LSTM_STEP(QC[7], 1, true) }

  // chunk 0 (first: no store at step 0), loads chunk 1 into qb
  LSTM_CHUNK(qa, qb, true, true)
  // chunks 1..62 in ping-pong pairs
  for (int p = 0; p < 31; ++p) {
    LSTM_CHUNK(qb, qa, true, false)
    LSTM_CHUNK(qa, qb, true, false)
  }
  // chunk 63 (last): no loads
  LSTM_CHUNK(qb, qa, false, false)

#undef LSTM_CHUNK
#undef LSTM_STEP

  if (lk == 0) *hptr = hprev;   // final step's h
}

// ---------------------------------------------------------------------------
// K4: emissions = h @ W_out^T + b_out.  H f16, W_out f16-packed in LDS, fdot2.
// ---------------------------------------------------------------------------
__global__ __launch_bounds__(256) void emis_k(
    const u16* __restrict__ Hb, const u32* __restrict__ Wout16,
    const float* __restrict__ b_out, float* __restrict__ em)
{
  __shared__ __align__(16) u32 wl2[24 * 128];   // 12 KB
  __shared__ float bo[24];
  const int tid = threadIdx.x;
  for (int i = tid; i < 3072; i += 256) wl2[i] = Wout16[i];
  if (tid < 24) bo[tid] = b_out[tid];
  __syncthreads();

  const int m = blockIdx.x * 256 + tid;
  float acc[24];
#pragma unroll
  for (int tg = 0; tg < 24; ++tg) acc[tg] = bo[tg];

  const u32* h2 = (const u32*)(Hb + (size_t)m * 256);
  for (int ck = 0; ck < 16; ++ck) {          // 8 f16 per chunk
    uint4 hv = *(const uint4*)(h2 + ck * 4);
#pragma unroll
    for (int tg = 0; tg < 24; ++tg) {
      u32x4v wv = *(const u32x4v*)&wl2[tg * 128 + ck * 4];
      float a = acc[tg];
      a = __builtin_amdgcn_fdot2(u2h2(hv.x), u2h2(wv.x), a, false);
      a = __builtin_amdgcn_fdot2(u2h2(hv.y), u2h2(wv.y), a, false);
      a = __builtin_amdgcn_fdot2(u2h2(hv.z), u2h2(wv.z), a, false);
      a = __builtin_amdgcn_fdot2(u2h2(hv.w), u2h2(wv.w), a, false);
      acc[tg] = a;
    }
  }
#pragma unroll
  for (int t6 = 0; t6 < 6; ++t6) {
    float4 o;
    o.x = acc[t6*4+0]; o.y = acc[t6*4+1]; o.z = acc[t6*4+2]; o.w = acc[t6*4+3];
    *(float4*)&em[(size_t)m * 24 + t6 * 4] = o;
  }
}

// ---------------------------------------------------------------------------
// K5: CRF forward scan, probability domain, all cross-lane via __shfl.
// ---------------------------------------------------------------------------
__device__ __forceinline__ int get_mask(const void* mp, int idx, bool byte_mode) {
  return byte_mode ? (int)((const unsigned char*)mp)[idx] : ((const int*)mp)[idx];
}

__global__ __launch_bounds__(64) void crf_k(
    const float* __restrict__ em, const int* __restrict__ tags,
    const void* __restrict__ maskp, const float* __restrict__ trans,
    const float* __restrict__ start_tr, const float* __restrict__ end_tr,
    float* __restrict__ out)
{
  const int b = blockIdx.x;
  const int tid = threadIdx.x;
  const bool byte_mode = (*(const u32*)maskp != 1u);
  const bool act = (tid < 48);
  const int j  = (tid < 24) ? tid : (act ? tid - 24 : 0);
  const int i0 = (tid < 24) ? 0 : 12;
  const int partner = (tid < 24) ? tid + 24 : tid - 24;

  int cnt = 0;
  for (int t = tid; t < TT; t += 64) cnt += get_mask(maskp, b * TT + t, byte_mode);
#pragma unroll
  for (int off = 32; off > 0; off >>= 1) cnt += __shfl_down(cnt, off);
  cnt = __shfl(cnt, 0);

  float Texp[12];
  if (act) {
#pragma unroll
    for (int k = 0; k < 12; ++k) Texp[k] = __expf(trans[(i0 + k) * 24 + j]);
  } else {
#pragma unroll
    for (int k = 0; k < 12; ++k) Texp[k] = 0.f;
  }

  float sc0 = act ? (start_tr[j] + em[(size_t)(b * TT) * 24 + j]) : -1e30f;
  float m = sc0;
#pragma unroll
  for (int off = 32; off > 0; off >>= 1) m = fmaxf(m, __shfl_xor(m, off));
  float P = act ? __expf(sc0 - m) : 0.f;
  float logC = m;

  float em_next = 0.f;
  if (act && cnt > 1) em_next = em[(size_t)(b * TT + 1) * 24 + j];

  for (int t = 1; t < cnt; ++t) {
    float em_cur = em_next;
    if (act && t + 1 < cnt) em_next = em[(size_t)(b * TT + t + 1) * 24 + j];

    float s0 = 0.f, s1 = 0.f, s2 = 0.f;
#pragma unroll
    for (int k = 0; k < 4; ++k)  s0 += __shfl(P, i0 + k)     * Texp[k];
#pragma unroll
    for (int k = 4; k < 8; ++k)  s1 += __shfl(P, i0 + k)     * Texp[k];
#pragma unroll
    for (int k = 8; k < 12; ++k) s2 += __shfl(P, i0 + k)     * Texp[k];
    float sh = (s0 + s1) + s2;
    float so = __shfl(sh, partner);
    float tot = sh + so;
    P = act ? (__expf(em_cur) * tot) : 0.f;

    if ((t & 3) == 0) {          // renormalize every 4 steps
      float mm = P;
#pragma unroll
      for (int off = 32; off > 0; off >>= 1) mm = fmaxf(mm, __shfl_xor(mm, off));
      P = P / mm;
      logC += __logf(mm);
    }
  }

  float z = (tid < 24) ? P * __expf(end_tr[tid]) : 0.f;
#pragma unroll
  for (int off = 32; off > 0; off >>= 1) z += __shfl_xor(z, off);
  float lzv = logC + __logf(z);

  float part = 0.f;
  for (int t = tid; t < TT; t += 64) {
    if (t >= 1 && t < cnt) {
      int tp = tags[b * TT + t - 1], tc = tags[b * TT + t];
      part += trans[tp * 24 + tc] + em[((size_t)(b * TT + t)) * 24 + tc];
    }
  }
#pragma unroll
  for (int off = 32; off > 0; off >>= 1) part += __shfl_down(part, off);
  if (tid == 0) {
    int t0g = tags[b * TT];
    float gold = start_tr[t0g] + em[(size_t)(b * TT) * 24 + t0g] + part;
    gold += end_tr[tags[b * TT + cnt - 1]];
    atomicAdd(out, (lzv - gold) * (1.0f / 128.0f));
  }
}

// ---------------------------------------------------------------------------
extern "C" void kernel_launch(void* const* d_in, const int* in_sizes, int n_in,
                              void* d_out, int out_size, void* d_ws, size_t ws_size,
                              hipStream_t stream) {
  const int*   x     = (const int*)d_in[0];
  const int*   tags  = (const int*)d_in[1];
  const void*  mask  = d_in[2];
  const float* emb   = (const float*)d_in[3];
  const float* Wih_f = (const float*)d_in[4];
  const float* Whh_f = (const float*)d_in[5];
  const float* bih_f = (const float*)d_in[6];
  const float* bhh_f = (const float*)d_in[7];
  const float* Wih_b = (const float*)d_in[8];
  const float* Whh_b = (const float*)d_in[9];
  const float* bih_b = (const float*)d_in[10];
  const float* bhh_b = (const float*)d_in[11];
  const float* W_out = (const float*)d_in[12];
  const float* b_out = (const float*)d_in[13];
  const float* trans = (const float*)d_in[14];
  const float* st_tr = (const float*)d_in[15];
  const float* en_tr = (const float*)d_in[16];

  u16*   Gb     = (u16*)d_ws;                              // [65536][1024] bf16
  u16*   Hb     = Gb + (size_t)65536 * 1024;               // [65536][256]  f16
  float* em     = (float*)(Hb + (size_t)65536 * 256);      // [65536][24]   f32
  float* bias   = em + (size_t)65536 * 24;                 // [1024]
  u16*   Wb     = (u16*)(bias + 1024);                     // [1024][128]   bf16
  u16*   Whhb   = Wb + 131072;                             // [2][512][128] bf16
  u32*   Wout16 = (u32*)(Whhb + 131072);                   // [24][128]     f16x2
  u16*   xe     = Hb;  // alias: xe dead before lstm writes Hb

  prep_k<<<512, 256, 0, stream>>>(Wih_f, Wih_b, Whh_f, Whh_b,
                                  bih_f, bhh_f, bih_b, bhh_b, W_out,
                                  Wb, Whhb, bias, Wout16);
  embed_k<<<8192, 256, 0, stream>>>(x, emb, xe);
  gates_mfma_k<<<dim3(8, 512), 256, 0, stream>>>(xe, Wb, bias, Gb);
  lstm_mfma_k<<<256, 512, 0, stream>>>(Gb, Whhb, Hb);
  emis_k<<<256, 256, 0, stream>>>(Hb, Wout16, b_out, em);
  (void)hipMemsetAsync(d_out, 0, sizeof(float), stream);
  crf_k<<<128, 64, 0, stream>>>(em, tags, mask, trans, st_tr, en_tr, (float*)d_out);
}